// Round 21
// baseline (11.785 us; speedup 1.0000x reference)
//
#include <hip/hip_runtime.h>

namespace {

typedef float v2f __attribute__((ext_vector_type(2)));

constexpr int kT   = 8;    // timesteps
constexpr int kB   = 256;  // batch
constexpr int kNQ  = 8;    // qubits per circuit
constexpr int kNB  = 8;    // blocks
constexpr int kD   = 64;   // features
constexpr int kNL  = 2;    // quantum layers
constexpr int kGateF = 8;
constexpr int kCircStride = 16 * kGateF + 4;   // 132: pad so u-strides hit distinct banks

// Walsh parity masks (validated r4-r20): wire-set of output w, bit j = wire j.
constexpr unsigned long long kMaskPacked =
    (0x54ULL << 0) | (0xA8ULL << 8) | (0x05ULL << 16) | (0x0AULL << 24) |
    (0x15ULL << 32) | (0x2AULL << 40) | (0x55ULL << 48) | (0xAAULL << 56);

__device__ __forceinline__ v2f mk(float a, float b) { v2f r; r.x = a; r.y = b; return r; }
__device__ __forceinline__ v2f swp(v2f v) { return __builtin_shufflevector(v, v, 1, 0); }

// ---------------- fast sincos of a/2 ----------------
__device__ __forceinline__ void fastsc(float a, float& s, float& c) {
#if __has_builtin(__builtin_amdgcn_sinf) && __has_builtin(__builtin_amdgcn_cosf)
    const float r = a * 0.07957747154594767f;   // 0.5 / (2*pi)
    s = __builtin_amdgcn_sinf(r);
    c = __builtin_amdgcn_cosf(r);
#else
    __sincosf(0.5f * a, &s, &c);
#endif
}

// B_j entry select: h_j if wire j in mask, else identity.
__device__ __forceinline__ void bsel(const float* __restrict__ hh, int j, unsigned mask,
                                     float& b00, float& b01r, float& b01i, float& b11) {
    const float* hp = hh + j * kGateF;
    const bool m = (mask >> j) & 1u;
    const float a = hp[0], hr = hp[1], hi = hp[2];
    b00  = m ? a   : 1.0f;
    b01r = m ? hr  : 0.0f;
    b01i = m ? hi  : 0.0f;
    b11  = m ? -a  : 1.0f;
}

// ---------------- symmetry-reduced DP, TWO samples interleaved -----------------------
// Algebra validated r20 (Hermitian chain A + single complex chain B, E = EA + 2*EB).
// This version runs two samples' chains in one lane: gate/hermitian LDS reads and
// B-coefficient selects are SHARED; sincos/rho/DP state duplicate as independent
// dependency chains (ILP x2). All [2]-indices are compile-time (unrolled).
__device__ __forceinline__ void simdp2(const float (&ang)[2][8],
                                       const float* __restrict__ g0,   // d0 gates (LDS)
                                       const float* __restrict__ hh,   // d1 herms (LDS)
                                       unsigned mask, float& E0out, float& E1out) {
    // per-wire density-matrix entries, per sample (gate reads shared across samples)
    float r00[2][8], r11[2][8], r01r[2][8], r01i[2][8];
#pragma unroll
    for (int j = 0; j < 8; ++j) {
        const float* gp = g0 + j * kGateF;
        const float ga = gp[0], gb = gp[1], gc = gp[2], gd = gp[3];
        const float ge = gp[4], gf = gp[5], gg = gp[6], gh = gp[7];
#pragma unroll
        for (int s = 0; s < 2; ++s) {
            float sn, cs;
            fastsc(ang[s][j], sn, cs);
            const float s0r = ga * cs + gc * sn, s0i = gb * cs + gd * sn;
            const float s1r = ge * cs + gg * sn, s1i = gf * cs + gh * sn;
            r00[s][j]  = s0r * s0r + s0i * s0i;
            r11[s][j]  = s1r * s1r + s1i * s1i;
            r01r[s][j] = s0r * s1r + s0i * s1i;   // sigma0 * conj(sigma1)
            r01i[s][j] = s0i * s1r - s0r * s1i;
        }
    }

    v2f D0[2], D1[2], Or_[2], Oi_[2];   // chain A (Hermitian, slices packed in v2f)
    v2f Pr[2], Pi[2], Qr[2], Qi[2];     // chain B (slice (0,1))

    // ---- init fused with step j=1 (B coeffs shared across samples) ----
    {
        float e00, e01r, e01i, e11;
        bsel(hh, 1, mask, e00, e01r, e01i, e11);
#pragma unroll
        for (int s = 0; s < 2; ++s) {
            const float c1r = r01r[s][1], c1i = r01i[s][1];
            // chain A
            const v2f q0 = mk(r00[s][0], r11[s][0]);
            const v2f m  = mk(r00[s][1], r11[s][1]);
            D0[s] = q0 * m * e00;
            D1[s] = q0 * swp(m) * e11;
            const v2f Orp = q0 * c1r;
            const v2f Oip = q0 * mk(c1i, -c1i);
            Or_[s] = e01r * Orp + e01i * Oip;     // * conj(B1_01)
            Oi_[s] = e01r * Oip - e01i * Orp;
            // chain B (z = rho0[0][1])
            const float zr = r01r[s][0], zi = r01i[s][0];
            const float w1r = zr * c1r - zi * c1i, w1i = zr * c1i + zi * c1r;   // z*c1
            const float w2r = zr * c1r + zi * c1i, w2i = zi * c1r - zr * c1i;   // z*conj(c1)
            Pr[s] = mk(w1r * e00, w2r * e11);
            Pi[s] = mk(w1i * e00, w2i * e11);
            const float ur = zr * r00[s][1], ui = zi * r00[s][1];
            const float vr = zr * r11[s][1], vi = zi * r11[s][1];
            Qr[s] = mk(ur * e01r + ui * e01i, vr * e01r - vi * e01i);
            Qi[s] = mk(ui * e01r - ur * e01i, vi * e01r + vr * e01i);
        }
    }

    // ---- steps j = 2..7 (bsel shared; two independent chains per step) ----
#pragma unroll
    for (int j = 2; j < 8; ++j) {
        float e00, e01r, e01i, e11;
        bsel(hh, j, mask, e00, e01r, e01i, e11);
#pragma unroll
        for (int s = 0; s < 2; ++s) {
            const float c00 = r00[s][j], c11 = r11[s][j];
            const float c01r = r01r[s][j], c01i = r01i[s][j];
            // chain A (Hermitian update)
            {
                const v2f Ta = c01r * Or_[s], Tb = c01i * Oi_[s];
                const v2f T1 = Ta - Tb, T2 = Ta + Tb;
                const v2f S00 = c00 * D0[s] + c11 * D1[s] + 2.0f * T1;
                const v2f S11 = c00 * D1[s] + c11 * D0[s] + 2.0f * T2;
                const float cps = c00 + c11, cms = c00 - c11;
                const v2f Dp = D0[s] + D1[s], Dm = D0[s] - D1[s];
                const v2f S01r = cps * Or_[s] + c01r * Dp;
                const v2f S01i = cms * Oi_[s] + c01i * Dm;
                D0[s] = e00 * S00;
                D1[s] = e11 * S11;
                Or_[s] = e01r * S01r + e01i * S01i;   // * conj(B01)
                Oi_[s] = e01r * S01i - e01i * S01r;
            }
            // chain B (general complex update)
            {
                const v2f Prs = swp(Pr[s]), Pis = swp(Pi[s]);
                const v2f Qrs = swp(Qr[s]), Qis = swp(Qi[s]);
                const v2f SPr = c00 * Pr[s] + c11 * Prs + c01r * (Qr[s] + Qrs) + c01i * (Qis - Qi[s]);
                const v2f SPi = c00 * Pi[s] + c11 * Pis + c01r * (Qi[s] + Qis) + c01i * (Qr[s] - Qrs);
                const v2f SQr = c00 * Qr[s] + c11 * Qrs + c01r * (Pr[s] + Prs) + c01i * (Pis - Pi[s]);
                const v2f SQi = c00 * Qi[s] + c11 * Qis + c01r * (Pi[s] + Pis) + c01i * (Pr[s] - Prs);
                const v2f Bd = mk(e00, e11);
                const v2f be = mk(e01i, -e01i);
                Pr[s] = Bd * SPr;
                Pi[s] = Bd * SPi;
                Qr[s] = e01r * SQr + be * SQi;        // lane x: conj(B01), lane y: B01
                Qi[s] = e01r * SQi - be * SQr;
            }
        }
    }

    // ---- final l_0 wrap: E = E_A + 2*E_B ----
    float e00, e01r, e01i, e11;
    bsel(hh, 0, mask, e00, e01r, e01i, e11);
#pragma unroll
    for (int s = 0; s < 2; ++s) {
        const float EA = D0[s].x * e00 + D0[s].y * e11 + D1[s].x * e11 + D1[s].y * e00
                       + 2.0f * (e01r * (Or_[s].x + Or_[s].y) + e01i * (Oi_[s].x - Oi_[s].y));
        const float EB = e01r * Pr[s].x + e01i * Pi[s].x + e01r * Pr[s].y - e01i * Pi[s].y
                       + e00 * Qr[s].x + e11 * Qr[s].y;
        const float E = EA + 2.0f * EB;
        if (s == 0) E0out = E; else E1out = E;
    }
}

// ---------------- single fused kernel: gate build (LDS) + both layers ----------------
// block = 256 threads = 4 waves, all sharing one timestep tt (128 wids/tt, 32
// blocks/tt). wave = (t, sample-pair); lane = (u:3, w:3) computes expval w of
// circuit u for BOTH samples of the pair.
__global__ __launch_bounds__(256) void fused_kernel(const float* __restrict__ x,
                                                    const float* __restrict__ theta,
                                                    float* __restrict__ out) {
    __shared__ float gl[kNL * kNB * kCircStride];   // 2112 floats = 8448 B

    const int tid  = threadIdx.x;
    const int wid  = blockIdx.x * 4 + (tid >> 6);
    const int lane = tid & 63;
    const int tt = wid >> 7;              // timestep (block-uniform: 32 blocks/tt)
    const int b0 = (wid & 127) << 1;      // first sample of pair
    const int u  = lane >> 3;             // circuit within timestep
    const int w  = lane & 7;              // output wire
    const unsigned mask = (unsigned)((kMaskPacked >> (w * 8)) & 0xFF);

    // ---- gate build: one slot per thread (coalesced theta reads) ----
    {
        const int l  = tid >> 7;
        const int uu = (tid >> 4) & 7;
        const int g  = tid & 15;         // d*8 + wire
        const int d  = g >> 3, ww = g & 7;
        const float* th = theta + ((((tt * kNL + l) * kNB + uu) * 2 + d) * kNQ + ww) * 3;
        const float phi = th[0], tht = th[1], omg = th[2];
        float st, ct, sp, cp, sm, cm;
        fastsc(tht, st, ct);
        fastsc(phi + omg, sp, cp);
        fastsc(phi - omg, sm, cm);
        const float u00r =  ct * cp, u00i = -ct * sp;
        const float u01r = -st * cm, u01i = -st * sm;
        const float u10r =  st * cm, u10i = -st * sm;
        const float u11r =  ct * cp, u11i =  ct * sp;
        float* o = &gl[(l * kNB + uu) * kCircStride + g * kGateF];
        if (d == 1) {
            // h = g^dag Z g (Hermitian, traceless)
            o[0] = (u00r * u00r + u00i * u00i) - (u10r * u10r + u10i * u10i);
            o[1] = (u00r * u01r + u00i * u01i) - (u10r * u11r + u10i * u11i);
            o[2] = (u00r * u01i - u00i * u01r) - (u10r * u11i - u10i * u11r);
        } else {
            o[0] = u00r;  o[1] = u00i;
            o[2] = u01r;  o[3] = u01i;
            o[4] = u10r;  o[5] = u10i;
            o[6] = u11r;  o[7] = u11i;
        }
    }
    __syncthreads();

    // ---- phase 0: layer-0 circuit (t,u), both samples ----
    float ang[2][8];
#pragma unroll
    for (int s = 0; s < 2; ++s) {
        const float* ab = x + (((b0 + s) * kT + tt) * kD + u * kNQ);
#pragma unroll
        for (int j = 0; j < 8; ++j) ang[s][j] = ab[j];
    }
    const float* base0 = &gl[u * kCircStride];
    float E0, E1;
    simdp2(ang, base0, base0 + 8 * kGateF, mask, E0, E1);

    // ---- redistribute: layer-1 circuit u needs H0[t,b,i*8+u] = lane i*8+u ----
#pragma unroll
    for (int i = 0; i < 8; ++i) {
        ang[0][i] = __shfl(E0, i * 8 + u, 64);
        ang[1][i] = __shfl(E1, i * 8 + u, 64);
    }

    // ---- phase 1: layer-1 circuit (t,u), both samples ----
    const float* base1 = &gl[(kNB + u) * kCircStride];
    simdp2(ang, base1, base1 + 8 * kGateF, mask, E0, E1);

    out[((b0 + 0) * kT + tt) * kD + lane] = E0;   // coalesced
    out[((b0 + 1) * kT + tt) * kD + lane] = E1;
}

}  // namespace

extern "C" void kernel_launch(void* const* d_in, const int* in_sizes, int n_in,
                              void* d_out, int out_size, void* d_ws, size_t ws_size,
                              hipStream_t stream) {
    const float* x     = (const float*)d_in[0];   // (B, T, D) fp32
    const float* theta = (const float*)d_in[1];   // (T, NL, NB, DEPTH, NQ, 3) fp32
    float* out = (float*)d_out;                   // (B, T, D) fp32

    // 8 timesteps x 128 sample-pairs = 1024 waves; 4 waves/block -> 256 blocks
    fused_kernel<<<kT * kB / 8, 256, 0, stream>>>(x, theta, out);
}

// Round 22
// 11.500 us; speedup vs baseline: 1.0248x; 1.0248x over previous
//
#include <hip/hip_runtime.h>

namespace {

typedef float v2f __attribute__((ext_vector_type(2)));

constexpr int kT   = 8;    // timesteps
constexpr int kB   = 256;  // batch
constexpr int kNQ  = 8;    // qubits per circuit
constexpr int kNB  = 8;    // blocks
constexpr int kD   = 64;   // features
constexpr int kNL  = 2;    // quantum layers
constexpr int kGateF = 8;
constexpr int kCircStride = 16 * kGateF + 4;   // 132: pad so u-strides hit distinct banks

// Walsh parity masks (validated r4-r21): wire-set of output w, bit j = wire j.
constexpr unsigned long long kMaskPacked =
    (0x54ULL << 0) | (0xA8ULL << 8) | (0x05ULL << 16) | (0x0AULL << 24) |
    (0x15ULL << 32) | (0x2AULL << 40) | (0x55ULL << 48) | (0xAAULL << 56);

__device__ __forceinline__ v2f mk(float a, float b) { v2f r; r.x = a; r.y = b; return r; }
__device__ __forceinline__ v2f swp(v2f v) { return __builtin_shufflevector(v, v, 1, 0); }

// ---------------- fast sincos of a/2 ----------------
__device__ __forceinline__ void fastsc(float a, float& s, float& c) {
#if __has_builtin(__builtin_amdgcn_sinf) && __has_builtin(__builtin_amdgcn_cosf)
    const float r = a * 0.07957747154594767f;   // 0.5 / (2*pi)
    s = __builtin_amdgcn_sinf(r);
    c = __builtin_amdgcn_cosf(r);
#else
    __sincosf(0.5f * a, &s, &c);
#endif
}

// B_j entry select: h_j if wire j in mask, else identity.
__device__ __forceinline__ void bsel(const float* __restrict__ hh, int j, unsigned mask,
                                     float& b00, float& b01r, float& b01i, float& b11) {
    const float* hp = hh + j * kGateF;
    const bool m = (mask >> j) & 1u;
    const float a = hp[0], hr = hp[1], hi = hp[2];
    b00  = m ? a   : 1.0f;
    b01r = m ? hr  : 0.0f;
    b01i = m ? hi  : 0.0f;
    b11  = m ? -a  : 1.0f;
}

// ---------------- symmetry-reduced 16-state transfer-matrix DP --------------------
// Base DP validated r15/r16; v2f slice-packing validated r18; conjugation-symmetry
// reduction validated r20: V_(b0,bp)[p][pp] = conj(V_(bp,b0)[pp][p]). Chain A =
// slices {(0,0),(1,1)}: HERMITIAN 2x2 each -> {D0,D1 real diag, O off-diag} packed
// over slices in v2f. Chain B = slice (0,1) only ((1,0) is its conjugate-transpose
// => same E). Total E = E_A + 2*E_B.
__device__ __forceinline__ float simdp(const float (&ang)[8],
                                       const float* __restrict__ g0,   // d0 gates (LDS)
                                       const float* __restrict__ hh,   // d1 herms (LDS)
                                       unsigned mask) {
    // per-wire density-matrix entries: rho = sigma sigma^dag
    float r00[8], r11[8], r01r[8], r01i[8];
#pragma unroll
    for (int j = 0; j < 8; ++j) {
        float sn, cs;
        fastsc(ang[j], sn, cs);
        const float* gp = g0 + j * kGateF;
        const float s0r = gp[0] * cs + gp[2] * sn, s0i = gp[1] * cs + gp[3] * sn;
        const float s1r = gp[4] * cs + gp[6] * sn, s1i = gp[5] * cs + gp[7] * sn;
        r00[j]  = s0r * s0r + s0i * s0i;
        r11[j]  = s1r * s1r + s1i * s1i;
        r01r[j] = s0r * s1r + s0i * s1i;   // sigma0 * conj(sigma1)
        r01i[j] = s0i * s1r - s0r * s1i;
    }

    v2f D0, D1, Or_, Oi_;      // chain A (Hermitian, slices packed in v2f)
    v2f Pr, Pi, Qr, Qi;        // chain B (slice (0,1): P=(V00,V11), Q=(V01,V10))

    // ---- init fused with step j=1: V = rho0[b0,bp] * rho1[p^b0, pp^bp] * B1[pp][p]
    {
        float e00, e01r, e01i, e11;
        bsel(hh, 1, mask, e00, e01r, e01i, e11);
        const float c1r = r01r[1], c1i = r01i[1];
        // chain A
        const v2f q0 = mk(r00[0], r11[0]);
        const v2f m  = mk(r00[1], r11[1]);
        D0 = q0 * m * e00;
        D1 = q0 * swp(m) * e11;
        const v2f Orp = q0 * c1r;                 // pre-B off-diag (r00*c1, r11*conj(c1))
        const v2f Oip = q0 * mk(c1i, -c1i);
        Or_ = e01r * Orp + e01i * Oip;            // * conj(B1_01)
        Oi_ = e01r * Oip - e01i * Orp;
        // chain B (z = rho0[0][1])
        const float zr = r01r[0], zi = r01i[0];
        const float w1r = zr * c1r - zi * c1i, w1i = zr * c1i + zi * c1r;   // z*c1
        const float w2r = zr * c1r + zi * c1i, w2i = zi * c1r - zr * c1i;   // z*conj(c1)
        Pr = mk(w1r * e00, w2r * e11);
        Pi = mk(w1i * e00, w2i * e11);
        const float ur = zr * r00[1], ui = zi * r00[1];   // z*r00'
        const float vr = zr * r11[1], vi = zi * r11[1];   // z*r11'
        Qr = mk(ur * e01r + ui * e01i, vr * e01r - vi * e01i);   // u*conj(B01), v*B01
        Qi = mk(ui * e01r - ur * e01i, vi * e01r + vr * e01i);
    }

    // ---- steps j = 2..7 ----
#pragma unroll
    for (int j = 2; j < 8; ++j) {
        float e00, e01r, e01i, e11;
        bsel(hh, j, mask, e00, e01r, e01i, e11);
        const float c00 = r00[j], c11 = r11[j], c01r = r01r[j], c01i = r01i[j];
        // chain A (Hermitian update)
        {
            const v2f Ta = c01r * Or_, Tb = c01i * Oi_;
            const v2f T1 = Ta - Tb, T2 = Ta + Tb;
            const v2f S00 = c00 * D0 + c11 * D1 + 2.0f * T1;
            const v2f S11 = c00 * D1 + c11 * D0 + 2.0f * T2;
            const float cps = c00 + c11, cms = c00 - c11;
            const v2f Dp = D0 + D1, Dm = D0 - D1;
            const v2f S01r = cps * Or_ + c01r * Dp;
            const v2f S01i = cms * Oi_ + c01i * Dm;
            D0 = e00 * S00;
            D1 = e11 * S11;
            Or_ = e01r * S01r + e01i * S01i;      // * conj(B01)
            Oi_ = e01r * S01i - e01i * S01r;
        }
        // chain B (general complex update; swaps are free op_sel)
        {
            const v2f Prs = swp(Pr), Pis = swp(Pi), Qrs = swp(Qr), Qis = swp(Qi);
            const v2f SPr = c00 * Pr + c11 * Prs + c01r * (Qr + Qrs) + c01i * (Qis - Qi);
            const v2f SPi = c00 * Pi + c11 * Pis + c01r * (Qi + Qis) + c01i * (Qr - Qrs);
            const v2f SQr = c00 * Qr + c11 * Qrs + c01r * (Pr + Prs) + c01i * (Pis - Pi);
            const v2f SQi = c00 * Qi + c11 * Qis + c01r * (Pi + Pis) + c01i * (Pr - Prs);
            const v2f Bd = mk(e00, e11);
            const v2f be = mk(e01i, -e01i);
            Pr = Bd * SPr;
            Pi = Bd * SPi;
            Qr = e01r * SQr + be * SQi;           // lane x: conj(B01), lane y: B01
            Qi = e01r * SQi - be * SQr;
        }
    }

    // ---- final l_0 wrap: E = E_A + 2*E_B ----
    float e00, e01r, e01i, e11;
    bsel(hh, 0, mask, e00, e01r, e01i, e11);
    const float EA = D0.x * e00 + D0.y * e11 + D1.x * e11 + D1.y * e00
                   + 2.0f * (e01r * (Or_.x + Or_.y) + e01i * (Oi_.x - Oi_.y));
    const float EB = e01r * Pr.x + e01i * Pi.x + e01r * Pr.y - e01i * Pi.y
                   + e00 * Qr.x + e11 * Qr.y;
    return EA + 2.0f * EB;
}

// ---------------- single fused kernel: gate build (LDS) + both layers ----------------
// block = 256 threads = 4 waves, all sharing one timestep tt (256 wids/tt).
// wave = (t, sample b); lane = (u:3, w:3) computes expval w of circuit u.
__global__ __launch_bounds__(256) void fused_kernel(const float* __restrict__ x,
                                                    const float* __restrict__ theta,
                                                    float* __restrict__ out) {
    __shared__ float gl[kNL * kNB * kCircStride];   // 2112 floats = 8448 B

    const int tid  = threadIdx.x;
    const int wid  = blockIdx.x * 4 + (tid >> 6);
    const int lane = tid & 63;
    const int tt = wid >> 8;          // timestep (block-uniform)
    const int b  = wid & 255;         // sample
    const int u  = lane >> 3;         // circuit within timestep
    const int w  = lane & 7;          // output wire
    const unsigned mask = (unsigned)((kMaskPacked >> (w * 8)) & 0xFF);

    // ---- gate build: one slot per thread (coalesced theta reads) ----
    {
        const int l  = tid >> 7;
        const int uu = (tid >> 4) & 7;
        const int g  = tid & 15;         // d*8 + wire
        const int d  = g >> 3, ww = g & 7;
        const float* th = theta + ((((tt * kNL + l) * kNB + uu) * 2 + d) * kNQ + ww) * 3;
        const float phi = th[0], tht = th[1], omg = th[2];
        float st, ct, sp, cp, sm, cm;
        fastsc(tht, st, ct);
        fastsc(phi + omg, sp, cp);
        fastsc(phi - omg, sm, cm);
        const float u00r =  ct * cp, u00i = -ct * sp;
        const float u01r = -st * cm, u01i = -st * sm;
        const float u10r =  st * cm, u10i = -st * sm;
        const float u11r =  ct * cp, u11i =  ct * sp;
        float* o = &gl[(l * kNB + uu) * kCircStride + g * kGateF];
        if (d == 1) {
            // h = g^dag Z g (Hermitian, traceless)
            o[0] = (u00r * u00r + u00i * u00i) - (u10r * u10r + u10i * u10i);
            o[1] = (u00r * u01r + u00i * u01i) - (u10r * u11r + u10i * u11i);
            o[2] = (u00r * u01i - u00i * u01r) - (u10r * u11i - u10i * u11r);
        } else {
            o[0] = u00r;  o[1] = u00i;
            o[2] = u01r;  o[3] = u01i;
            o[4] = u10r;  o[5] = u10i;
            o[6] = u11r;  o[7] = u11i;
        }
    }
    __syncthreads();

    // ---- phase 0: layer-0 circuit (t,u), angles from x ----
    float ang[8];
    {
        const float* ab = x + ((b * kT + tt) * kD + u * kNQ);
#pragma unroll
        for (int j = 0; j < 8; ++j) ang[j] = ab[j];
    }
    const float* base0 = &gl[u * kCircStride];
    float E = simdp(ang, base0, base0 + 8 * kGateF, mask);

    // ---- redistribute: layer-1 circuit u needs H0[t,b,i*8+u] = lane i*8+u ----
#pragma unroll
    for (int i = 0; i < 8; ++i) ang[i] = __shfl(E, i * 8 + u, 64);

    // ---- phase 1: layer-1 circuit (t,u) ----
    const float* base1 = &gl[(kNB + u) * kCircStride];
    E = simdp(ang, base1, base1 + 8 * kGateF, mask);

    out[(b * kT + tt) * kD + u * kNQ + w] = E;   // coalesced: 64 consecutive floats/wave
}

}  // namespace

extern "C" void kernel_launch(void* const* d_in, const int* in_sizes, int n_in,
                              void* d_out, int out_size, void* d_ws, size_t ws_size,
                              hipStream_t stream) {
    const float* x     = (const float*)d_in[0];   // (B, T, D) fp32
    const float* theta = (const float*)d_in[1];   // (T, NL, NB, DEPTH, NQ, 3) fp32
    float* out = (float*)d_out;                   // (B, T, D) fp32

    // single kernel: 8 timesteps x 256 samples = 2048 waves; 4 waves/block
    fused_kernel<<<kT * kB / 4, 256, 0, stream>>>(x, theta, out);
}